// Round 7
// baseline (197.596 us; speedup 1.0000x reference)
//
#include <hip/hip_runtime.h>
#include <math.h>

#define H 1024
#define HEADS 16
#define DH 64
#define FFN_DIM 2048
#define EPS 1e-5f
#define NB 4
#define LL 1024
#define M_ROWS 4096

typedef __attribute__((ext_vector_type(8))) short bf16x8;
typedef __attribute__((ext_vector_type(4))) float f32x4;

__device__ __forceinline__ ushort f2bf(float x) {
    union { float f; unsigned u; } c; c.f = x;
    unsigned u = c.u;
    u += 0x7FFFu + ((u >> 16) & 1u);
    return (ushort)(u >> 16);
}

// pack two fp32 -> two bf16 (round-half-up), b in high half
__device__ __forceinline__ unsigned pack2bf(float a, float b) {
    union { float f; unsigned u; } ca, cb; ca.f = a; cb.f = b;
    const unsigned ua = ca.u + 0x8000u;
    const unsigned ub = cb.u + 0x8000u;
    return (ua >> 16) | (ub & 0xFFFF0000u);
}

#define GLL(gp, lp)                                                         \
    __builtin_amdgcn_global_load_lds(                                       \
        (const __attribute__((address_space(1))) void*)(gp),                \
        (__attribute__((address_space(3))) void*)(lp), 16, 0, 0)

#define WAITV4() asm volatile("s_waitcnt vmcnt(4)" ::: "memory")
#define WAITV2() asm volatile("s_waitcnt vmcnt(2)" ::: "memory")
#define WAITV0() asm volatile("s_waitcnt vmcnt(0)" ::: "memory")
#define BAR() __builtin_amdgcn_s_barrier()

// ------------- bf16 MFMA GEMM: 8 waves, 2-slot dbuf, counted vmcnt -------
// A: M x K bf16 row-major.  Bt: N x K bf16 row-major (B transposed).
// C = (A@B + bias) [+relu].  Split-K via gridDim.z (z==0 adds bias,
// fp32 partials to Cf0/Cf1).  qkv: col c -> segment c/1024.
__global__ __launch_bounds__(512, 8)
void gemm_bf16(const ushort* __restrict__ A, const ushort* __restrict__ Bt,
               const float* __restrict__ bias, float* __restrict__ Cf0,
               float* __restrict__ Cf1, ushort* __restrict__ Cb,
               int M, int N, int K, int relu, int qkv)
{
    __shared__ ushort As[2][128 * 32];   // 2 x 8 KB
    __shared__ ushort Bs[2][128 * 32];
    const int tid = threadIdx.x;         // 0..511, 8 waves
    const int l = tid & 63, w = tid >> 6;
    const int wr = w >> 2, wc = w & 3;   // wave tile: 64 rows x 32 cols
    const int g = l >> 4, c0 = l & 15;
    const int brow = blockIdx.y * 128, bcol = blockIdx.x * 128;
    const int z = blockIdx.z;
    const int Ksub = K / gridDim.z;
    const int NS = Ksub >> 5;

    const ushort* Abase = A + (size_t)brow * K + (size_t)z * Ksub;
    const ushort* Bbase = Bt + (size_t)bcol * K + (size_t)z * Ksub;

    f32x4 acc[4][2];
    #pragma unroll
    for (int mi = 0; mi < 4; ++mi)
        #pragma unroll
        for (int ni = 0; ni < 2; ++ni)
            acc[mi][ni] = (f32x4)0.0f;

    auto stage = [&](int buf, int k0) {  // 2 GLL per wave
        const int row = tid >> 2, cp = tid & 3;
        const int c = cp ^ ((row >> 1) & 3);
        const ushort* ga = Abase + (size_t)row * K + k0 + c * 8;
        const ushort* gb = Bbase + (size_t)row * K + k0 + c * 8;
        ushort* la = As[buf] + (size_t)w * 512;   // + lane*16B by HW
        ushort* lb = Bs[buf] + (size_t)w * 512;
        GLL(ga, la);
        GLL(gb, lb);
    };

    stage(0, 0);
    int cur = 0;
    for (int t = 0; t < NS; ++t) {
        if (t + 1 < NS) { stage(cur ^ 1, (t + 1) << 5); WAITV2(); }
        else            { WAITV0(); }
        BAR();

        bf16x8 af[4], bf[2];
        #pragma unroll
        for (int mi = 0; mi < 4; ++mi) {
            const int row = wr * 64 + mi * 16 + c0;
            const int cc = g ^ ((row >> 1) & 3);
            af[mi] = *(const bf16x8*)&As[cur][row * 32 + cc * 8];
        }
        #pragma unroll
        for (int ni = 0; ni < 2; ++ni) {
            const int row = wc * 32 + ni * 16 + c0;
            const int cc = g ^ ((row >> 1) & 3);
            bf[ni] = *(const bf16x8*)&Bs[cur][row * 32 + cc * 8];
        }
        __builtin_amdgcn_s_setprio(1);
        #pragma unroll
        for (int mi = 0; mi < 4; ++mi)
            #pragma unroll
            for (int ni = 0; ni < 2; ++ni)
                acc[mi][ni] = __builtin_amdgcn_mfma_f32_16x16x32_bf16(
                    af[mi], bf[ni], acc[mi][ni], 0, 0, 0);
        __builtin_amdgcn_s_setprio(0);
        BAR();
        cur ^= 1;
    }

    float* Cf = (z == 0) ? Cf0 : Cf1;
    const int colg0 = bcol + wc * 32 + c0;
    const int rbase = brow + wr * 64 + (g << 2);
    const int seg   = qkv ? (bcol >> 10) : 0;
    const int Nw    = qkv ? 1024 : N;
    ushort* outb    = qkv ? (Cb + (size_t)seg * 4194304u) : Cb;
    #pragma unroll
    for (int ni = 0; ni < 2; ++ni) {
        const int colg = colg0 + ni * 16;
        const int colw = qkv ? (colg & 1023) : colg;
        const float bv = (z == 0) ? bias[colg] : 0.0f;
        #pragma unroll
        for (int mi = 0; mi < 4; ++mi) {
            #pragma unroll
            for (int j = 0; j < 4; ++j) {
                float v = acc[mi][ni][j] + bv;
                if (relu) v = fmaxf(v, 0.0f);
                const size_t off = (size_t)(rbase + mi * 16 + j) * Nw + colw;
                if (Cf) Cf[off] = v;
                if (Cb) outb[off] = f2bf(v);
            }
        }
    }
}

// ---------------- fused QKVO weight transpose (H x H each) ---------------
__global__ __launch_bounds__(256)
void transpose_qkvo(const float* __restrict__ Wq, const float* __restrict__ Wk,
                    const float* __restrict__ Wv, const float* __restrict__ Wo,
                    ushort* __restrict__ Dq, ushort* __restrict__ Dk,
                    ushort* __restrict__ Dv, ushort* __restrict__ Do_)
{
    const float* W; ushort* D; float sc;
    switch (blockIdx.z) {
        case 0:  W = Wq; D = Dq;  sc = 0.03125f; break;
        case 1:  W = Wk; D = Dk;  sc = 0.03125f; break;
        case 2:  W = Wv; D = Dv;  sc = 1.0f;     break;
        default: W = Wo; D = Do_; sc = 1.0f;     break;
    }
    __shared__ float t[32][33];
    const int n0 = blockIdx.x * 32, k0 = blockIdx.y * 32;
    const int tx = threadIdx.x & 31, ty = threadIdx.x >> 5;
    #pragma unroll
    for (int r = 0; r < 4; ++r)
        t[ty + r * 8][tx] = W[(size_t)(k0 + ty + r * 8) * H + n0 + tx];
    __syncthreads();
    #pragma unroll
    for (int r = 0; r < 4; ++r)
        D[(size_t)(n0 + ty + r * 8) * H + k0 + tx] =
            f2bf(t[tx][ty + r * 8] * sc);
}

// ---------------- generic weight transpose (FFN) -------------------------
__global__ __launch_bounds__(256)
void transpose_to_bf16(const float* __restrict__ W, ushort* __restrict__ Wt,
                       int K, int N, float scale)
{
    __shared__ float t[32][33];
    const int n0 = blockIdx.x * 32, k0 = blockIdx.y * 32;
    const int tx = threadIdx.x & 31, ty = threadIdx.x >> 5;
    #pragma unroll
    for (int r = 0; r < 4; ++r)
        t[ty + r * 8][tx] = W[(size_t)(k0 + ty + r * 8) * N + n0 + tx];
    __syncthreads();
    #pragma unroll
    for (int r = 0; r < 4; ++r)
        Wt[(size_t)(n0 + ty + r * 8) * K + k0 + tx] =
            f2bf(t[tx][ty + r * 8] * scale);
}

// ---------------- per-head V transpose: [1024 j][64 d] -> [64 d][1024 j] --
__global__ __launch_bounds__(256)
void transpose_v(const ushort* __restrict__ V, ushort* __restrict__ Vt)
{
    const int nh = blockIdx.y, jt = blockIdx.x;
    const size_t base = (size_t)nh << 16;
    __shared__ ushort t[64][68];
    const int tid = threadIdx.x;
    #pragma unroll
    for (int pass = 0; pass < 4; ++pass) {
        const int j = pass * 16 + (tid >> 4);
        const int d0 = (tid & 15) * 4;
        ushort4 v = *(const ushort4*)&V[base + (size_t)(jt * 64 + j) * 64 + d0];
        t[d0 + 0][j] = v.x; t[d0 + 1][j] = v.y;
        t[d0 + 2][j] = v.z; t[d0 + 3][j] = v.w;
    }
    __syncthreads();
    #pragma unroll
    for (int pass = 0; pass < 4; ++pass) {
        const int d = pass * 16 + (tid >> 4);
        const int j0 = (tid & 15) * 4;
        ushort4 o;
        o.x = t[d][j0 + 0]; o.y = t[d][j0 + 1];
        o.z = t[d][j0 + 2]; o.w = t[d][j0 + 3];
        *(ushort4*)&Vt[base + (size_t)d * 1024 + jt * 64 + j0] = o;
    }
}

// ---------------- fp32 -> bf16 cast -------------------------------------
__global__ __launch_bounds__(256)
void f32_to_bf16(const float* __restrict__ in, ushort* __restrict__ out, int n4)
{
    const int i = blockIdx.x * blockDim.x + threadIdx.x;
    if (i < n4) {
        float4 v = *reinterpret_cast<const float4*>(&in[i * 4]);
        ushort4 o;
        o.x = f2bf(v.x); o.y = f2bf(v.y); o.z = f2bf(v.z); o.w = f2bf(v.w);
        *reinterpret_cast<ushort4*>(&out[i * 4]) = o;
    }
}

// ---------------- QKV bias concat + mask tile flags ----------------------
__global__ void build_bias_qkv(const float* __restrict__ bq,
                               const float* __restrict__ bk,
                               const float* __restrict__ bv,
                               float* __restrict__ out)
{
    const int i = blockIdx.x * 256 + threadIdx.x;
    if (i >= 3072) return;
    float v;
    if (i < 1024) v = bq[i] * 0.03125f;
    else if (i < 2048) v = bk[i - 1024] * 0.03125f;
    else v = bv[i - 2048];
    out[i] = v;
}

__global__ void mask_flags(const int* __restrict__ mask, int* __restrict__ fl)
{
    const int t = threadIdx.x;   // 64 = NB*16 tiles
    if (t < NB * 16) {
        const int n = t >> 4, tile = t & 15;
        int any = 0;
        for (int j = 0; j < 64; ++j)
            any |= (mask[n * LL + tile * 64 + j] == 0);
        fl[t] = any;
    }
}

// ------------- MFMA flash attention: swapped QK^T, packed P --------------
// Per head: Q,K = [1024][64] bf16 (pre-scaled by 1/32 each), Vt = [64][1024].
// s = mfma(K,Q): lane (g,c0) holds P[q=c0][key=16nb+4g+jr] -> 4 consecutive
// keys per fragment -> packed ds_write_b64 into Ps[q][key] (granule-XOR swz).
__global__ __launch_bounds__(256)
void attn_mfma(const ushort* __restrict__ Q, const ushort* __restrict__ K,
               const ushort* __restrict__ Vt, const int* __restrict__ mask,
               const int* __restrict__ mflags, ushort* __restrict__ ctx)
{
    const int nh = blockIdx.y;
    const int n  = nh >> 4;
    const int qb = blockIdx.x;
    const size_t hb = (size_t)nh << 16;
    const ushort* Qh = Q + hb;
    const ushort* Kh = K + hb;
    const ushort* Vh = Vt + hb;
    ushort* Ch = ctx + hb;

    __shared__ ushort Ks[2][64 * 64];
    __shared__ ushort Vs[2][64 * 64];
    __shared__ ushort Ps[4][16 * 64];   // per-wave [q][key], 8B-granule swz

    const int tid = threadIdx.x;
    const int l = tid & 63, w = tid >> 6;
    const int g = l >> 4, c0 = l & 15;
    const int fsw = (c0 & 7) << 1;      // even granule swizzle

    unsigned fbits = 0;
    #pragma unroll
    for (int tt = 0; tt < 16; ++tt)
        fbits |= (unsigned)(mflags[n * 16 + tt] != 0) << tt;

    const ushort* qrow = Qh + (size_t)(qb * 64 + w * 16 + c0) * 64;
    const bf16x8 qf0 = *(const bf16x8*)(qrow + g * 8);
    const bf16x8 qf1 = *(const bf16x8*)(qrow + 32 + g * 8);

    f32x4 Oacc[4];
    #pragma unroll
    for (int nd = 0; nd < 4; ++nd) Oacc[nd] = (f32x4)0.0f;
    float lp = 0.0f;                    // partial sum for q = c0

    auto stage = [&](int buf, int t) {   // 4 GLL per wave
        #pragma unroll
        for (int i = 0; i < 2; ++i) {
            const int slot = i * 256 + tid;
            const int r = slot >> 3, p = slot & 7;
            const int c = p ^ (r & 7);
            const ushort* gk = Kh + (size_t)(t * 64 + r) * 64 + c * 8;
            const ushort* gv = Vh + (size_t)r * 1024 + t * 64 + c * 8;
            ushort* lk = Ks[buf] + (size_t)(i * 256 + w * 64) * 8;
            ushort* lv = Vs[buf] + (size_t)(i * 256 + w * 64) * 8;
            GLL(gk, lk);
            GLL(gv, lv);
        }
    };

    stage(0, 0);
    int cur = 0;
    for (int t = 0; t < 16; ++t) {
        if (t < 15) { stage(cur ^ 1, t + 1); WAITV4(); }
        else        { WAITV0(); }
        BAR();

        // S^T = K @ Q^T : col = q = c0; rows = keys 16nb + 4g + jr
        f32x4 s[4];
        #pragma unroll
        for (int nb = 0; nb < 4; ++nb) {
            s[nb] = (f32x4)0.0f;
            const int row = nb * 16 + c0;           // K row = key
            const int cc0 = g ^ (row & 7);
            const int cc1 = (4 + g) ^ (row & 7);
            bf16x8 kf0 = *(const bf16x8*)&Ks[cur][row * 64 + cc0 * 8];
            bf16x8 kf1 = *(const bf16x8*)&Ks[cur][row * 64 + cc1 * 8];
            __builtin_amdgcn_s_setprio(1);
            s[nb] = __builtin_amdgcn_mfma_f32_16x16x32_bf16(kf0, qf0, s[nb], 0, 0, 0);
            s[nb] = __builtin_amdgcn_mfma_f32_16x16x32_bf16(kf1, qf1, s[nb], 0, 0, 0);
            __builtin_amdgcn_s_setprio(0);
        }
        if (fbits >> t & 1) {             // uniform branch; rare path
            #pragma unroll
            for (int nb = 0; nb < 4; ++nb)
                #pragma unroll
                for (int jr = 0; jr < 4; ++jr) {
                    const int key = 16 * nb + 4 * g + jr;
                    if (mask[n * LL + t * 64 + key] == 0)
                        s[nb][jr] = -INFINITY;
                }
        }
        // fixed-max softmax: P = exp(s); per-lane scalar row-sum (q = c0)
        #pragma unroll
        for (int nb = 0; nb < 4; ++nb)
            #pragma unroll
            for (int jr = 0; jr < 4; ++jr) {
                const float pv = __expf(s[nb][jr]);
                s[nb][jr] = pv;
                lp += pv;
            }

        // P -> LDS: 4 keys packed per fragment, one b64 per nb
        ushort* Pw = Ps[w];
        #pragma unroll
        for (int nb = 0; nb < 4; ++nb) {
            const int gi = (4 * nb + g) ^ fsw;
            uint2 pk;
            pk.x = pack2bf(s[nb][0], s[nb][1]);
            pk.y = pack2bf(s[nb][2], s[nb][3]);
            *(uint2*)&Pw[c0 * 64 + gi * 4] = pk;
        }
        // P A-fragments: q = c0, key chunks [8g..8g+7] and [32+8g..+7]
        const bf16x8 pa0 = *(const bf16x8*)&Pw[c0 * 64 + ((2 * g) ^ fsw) * 4];
        const bf16x8 pa1 = *(const bf16x8*)&Pw[c0 * 64 + ((8 + 2 * g) ^ fsw) * 4];
        // O += P @ V
        #pragma unroll
        for (int nd = 0; nd < 4; ++nd) {
            const int row = nd * 16 + c0;           // Vs row = d
            const int cc0 = g ^ (row & 7);
            const int cc1 = (4 + g) ^ (row & 7);
            bf16x8 vf0 = *(const bf16x8*)&Vs[cur][row * 64 + cc0 * 8];
            bf16x8 vf1 = *(const bf16x8*)&Vs[cur][row * 64 + cc1 * 8];
            __builtin_amdgcn_s_setprio(1);
            Oacc[nd] = __builtin_amdgcn_mfma_f32_16x16x32_bf16(pa0, vf0, Oacc[nd], 0, 0, 0);
            Oacc[nd] = __builtin_amdgcn_mfma_f32_16x16x32_bf16(pa1, vf1, Oacc[nd], 0, 0, 0);
            __builtin_amdgcn_s_setprio(0);
        }
        BAR();
        cur ^= 1;
    }

    // total row sums: reduce over g groups (lanes differing in bits 4-5)
    float v = lp;
    v += __shfl_xor(v, 16, 64);
    v += __shfl_xor(v, 32, 64);       // v = sum for q = c0
    // gather sums for this lane's output rows q = 4g + jr
    float invq[4];
    #pragma unroll
    for (int jr = 0; jr < 4; ++jr) {
        const int src = 20 * g + jr;  // lane with c0 = 4g + jr
        invq[jr] = 1.0f / __shfl(v, src, 64);
    }
    #pragma unroll
    for (int nd = 0; nd < 4; ++nd) {
        #pragma unroll
        for (int jr = 0; jr < 4; ++jr) {
            const int row = qb * 64 + w * 16 + 4 * g + jr;
            Ch[(size_t)row * 64 + nd * 16 + c0] = f2bf(Oacc[nd][jr] * invq[jr]);
        }
    }
}

// ---------------- LayerNorm + residual (optionally 2-input sum) ----------
__global__ __launch_bounds__(256)
void ln_residual(const float* __restrict__ X, const float* __restrict__ X2,
                 const float* __restrict__ g, const float* __restrict__ b,
                 float* __restrict__ outf, ushort* __restrict__ outb)
{
    const int row = blockIdx.x;
    const int tid = threadIdx.x;
    float4 xv = *reinterpret_cast<const float4*>(&X[(size_t)row * H + tid * 4]);
    if (X2) {
        float4 yv = *reinterpret_cast<const float4*>(&X2[(size_t)row * H + tid * 4]);
        xv.x += yv.x; xv.y += yv.y; xv.z += yv.z; xv.w += yv.w;
    }
    float s = xv.x + xv.y + xv.z + xv.w;
    __shared__ float red[8];
    const int lane = tid & 63, wave = tid >> 6;
    #pragma unroll
    for (int off = 32; off > 0; off >>= 1) s += __shfl_down(s, off);
    if (lane == 0) red[wave] = s;
    __syncthreads();
    if (tid == 0)
        red[0] = (red[0] + red[1] + red[2] + red[3]) * (1.0f / H);
    __syncthreads();
    const float mu = red[0];
    const float d0 = xv.x - mu, d1 = xv.y - mu, d2 = xv.z - mu, d3 = xv.w - mu;
    float s2 = d0 * d0 + d1 * d1 + d2 * d2 + d3 * d3;
    #pragma unroll
    for (int off = 32; off > 0; off >>= 1) s2 += __shfl_down(s2, off);
    if (lane == 0) red[4 + wave] = s2;
    __syncthreads();
    if (tid == 0) {
        const float var = (red[4] + red[5] + red[6] + red[7]) * (1.0f / H);
        red[4] = rsqrtf(var + EPS);
    }
    __syncthreads();
    const float rstd = red[4];
    float4 gv = *reinterpret_cast<const float4*>(&g[tid * 4]);
    float4 bv = *reinterpret_cast<const float4*>(&b[tid * 4]);
    float4 ov;
    ov.x = d0 * rstd * gv.x + bv.x + xv.x;
    ov.y = d1 * rstd * gv.y + bv.y + xv.y;
    ov.z = d2 * rstd * gv.z + bv.z + xv.z;
    ov.w = d3 * rstd * gv.w + bv.w + xv.w;
    if (outf)
        *reinterpret_cast<float4*>(&outf[(size_t)row * H + tid * 4]) = ov;
    if (outb) {
        ushort4 ob;
        ob.x = f2bf(ov.x); ob.y = f2bf(ov.y);
        ob.z = f2bf(ov.z); ob.w = f2bf(ov.w);
        *reinterpret_cast<ushort4*>(&outb[(size_t)row * H + tid * 4]) = ob;
    }
}

__global__ void mask_to_float(const int* __restrict__ m, float* __restrict__ o,
                              int n)
{
    const int i = blockIdx.x * blockDim.x + threadIdx.x;
    if (i < n) o[i] = (float)m[i];
}

extern "C" void kernel_launch(void* const* d_in, const int* in_sizes, int n_in,
                              void* d_out, int out_size, void* d_ws, size_t ws_size,
                              hipStream_t stream)
{
    const float* X    = (const float*)d_in[0];
    const int*   mask = (const int*)d_in[1];
    const float* Wq   = (const float*)d_in[2];
    const float* bq   = (const float*)d_in[3];
    const float* Wk   = (const float*)d_in[4];
    const float* bk   = (const float*)d_in[5];
    const float* Wv   = (const float*)d_in[6];
    const float* bv   = (const float*)d_in[7];
    const float* Wo   = (const float*)d_in[8];
    const float* bo   = (const float*)d_in[9];
    const float* g1   = (const float*)d_in[10];
    const float* bln1 = (const float*)d_in[11];
    const float* W1   = (const float*)d_in[12];
    const float* b1   = (const float*)d_in[13];
    const float* W2   = (const float*)d_in[14];
    const float* b2   = (const float*)d_in[15];
    const float* g2   = (const float*)d_in[16];
    const float* bln2 = (const float*)d_in[17];

    char* wsb = (char*)d_ws;
    const size_t MB = 1u << 20;
    // [0,24): QKV bf16 segs (Q@0, K@8MB, V@16MB)
    ushort* Qb16 = (ushort*)(wsb);
    ushort* Vb16 = (ushort*)(wsb + 16 * MB);
    // [24,32): Xb -> (after QKV gemm) ctxb
    ushort* Xb   = (ushort*)(wsb + 24 * MB);
    ushort* ctxb = (ushort*)(wsb + 24 * MB);
    // [32,40): Vtb
    ushort* Vtb  = (ushort*)(wsb + 32 * MB);
    // [40,48): weights (Wqkvt 6MB + Wot 2MB; later W1t 4MB + W2t 4MB)
    ushort* Wqkvt = (ushort*)(wsb + 40 * MB);
    ushort* Wot   = (ushort*)(wsb + 46 * MB);
    ushort* W1t   = (ushort*)(wsb + 40 * MB);
    ushort* W2t   = (ushort*)(wsb + 44 * MB);
    // [48,64): biasqkv+mfl early -> Wo partial P1 -> Fb
    float*  biasqkv = (float*)(wsb + 48 * MB);
    int*    mfl     = (int*)(wsb + 48 * MB + 16384);
    float*  P1      = (float*)(wsb + 48 * MB);
    ushort* Fb      = (ushort*)(wsb + 48 * MB);
    // Wo partial P0 over dead Q/K segs; x1b over dead V seg
    float*  P0  = (float*)(wsb);
    ushort* x1b = (ushort*)(wsb + 16 * MB);
    // FFN2 partials: Q0 over dead P0, Q1 over dead ctxb+Vtb
    float*  Q0  = (float*)(wsb);
    float*  Q1  = (float*)(wsb + 24 * MB);

    dim3 blk(256), gblk(512);

    f32_to_bf16<<<dim3(M_ROWS * H / 4 / 256), blk, 0, stream>>>(X, Xb, M_ROWS * H / 4);
    transpose_qkvo<<<dim3(32, 32, 4), blk, 0, stream>>>(
        Wq, Wk, Wv, Wo, Wqkvt, Wqkvt + 1024 * 1024, Wqkvt + 2048 * 1024, Wot);
    build_bias_qkv<<<dim3(12), blk, 0, stream>>>(bq, bk, bv, biasqkv);
    mask_flags<<<dim3(1), dim3(64), 0, stream>>>(mask, mfl);

    // fused QKV: N=3072, bf16 segments out
    gemm_bf16<<<dim3(24, 32, 1), gblk, 0, stream>>>(
        Xb, Wqkvt, biasqkv, nullptr, nullptr, Qb16, M_ROWS, 3072, H, 0, 1);
    transpose_v<<<dim3(16, NB * HEADS), blk, 0, stream>>>(Vb16, Vtb);

    attn_mfma<<<dim3(16, NB * HEADS), blk, 0, stream>>>(
        Qb16, Qb16 + 4194304u, Vtb, mask, mfl, ctxb);

    // Wo: split-K x2 -> fp32 partials P0,P1
    gemm_bf16<<<dim3(8, 32, 2), gblk, 0, stream>>>(
        ctxb, Wot, bo, P0, P1, nullptr, M_ROWS, H, H, 0, 0);
    ln_residual<<<dim3(M_ROWS), blk, 0, stream>>>(P0, P1, g1, bln1, nullptr, x1b);

    transpose_to_bf16<<<dim3(FFN_DIM / 32, H / 32), blk, 0, stream>>>(W1, W1t, H, FFN_DIM, 1.0f);
    transpose_to_bf16<<<dim3(H / 32, FFN_DIM / 32), blk, 0, stream>>>(W2, W2t, FFN_DIM, H, 1.0f);

    // FFN1: relu, bf16 out
    gemm_bf16<<<dim3(16, 32, 1), gblk, 0, stream>>>(
        x1b, W1t, b1, nullptr, nullptr, Fb, M_ROWS, FFN_DIM, H, 1, 0);
    // FFN2: split-K x2 -> fp32 partials Q0,Q1
    gemm_bf16<<<dim3(8, 32, 2), gblk, 0, stream>>>(
        Fb, W2t, b2, Q0, Q1, nullptr, M_ROWS, H, FFN_DIM, 0, 0);

    ln_residual<<<dim3(M_ROWS), blk, 0, stream>>>(Q0, Q1, g2, bln2, (float*)d_out, nullptr);

    mask_to_float<<<dim3((NB * LL + 255) / 256), blk, 0, stream>>>(
        mask, (float*)d_out + (size_t)M_ROWS * H, NB * LL);
}